// Round 2
// baseline (286.634 us; speedup 1.0000x reference)
//
#include <hip/hip_runtime.h>
#include <math.h>

#define T_TOKENS 16384
#define HDIM     2048
#define NEXP     128
#define TOPK     8

#define BK    64                 // k per chunk (2 MFMA k-steps)
#define NCH   (HDIM / BK)        // 32 chunks
#define TM    32                 // tokens per block

#define F16_MIN_NORM    6.1035156e-05f
#define SPLIT_SCALE     4096.0f
#define INV_SPLIT_SCALE 2.44140625e-04f   // 2^-12

typedef __attribute__((ext_vector_type(8))) _Float16 f16x8;  // A/B frag: 4 VGPR
typedef __attribute__((ext_vector_type(4))) float    f32x4;  // C/D frag + loads

// x = hi + lo*2^-12 (f16 RNE each); residual <= 2^-24|x|. Numerics verified R3-R8.
__device__ __forceinline__ void f16split(float f, _Float16& hi, _Float16& lo) {
    _Float16 h = (_Float16)f;
    float back = (float)h;
    if (fabsf(f) < F16_MIN_NORM) { h = (_Float16)0.f; back = 0.f; }
    lo = (_Float16)((f - back) * SPLIT_SCALE);
    hi = h;
}

// ---- prep: split w AND repack into MFMA B-frag order (verified R5-R8, unchanged) ----
// packed[s]: ((kk*8 + nt)*64 + lane) * 8 f16; kk = global 32-k step, nt = expert/16.
__global__ __launch_bounds__(256) void pack_w(const float* __restrict__ w,
                                              unsigned short* __restrict__ wp1,
                                              unsigned short* __restrict__ wp2) {
    int p = blockIdx.x * 256 + threadIdx.x;       // 0 .. 64*8*64-1
    int lane = p & 63, nt = (p >> 6) & 7, kk = p >> 9;
    int col = lane & 15, quad = lane >> 4;
    const float* src = w + (size_t)(nt * 16 + col) * HDIM + kk * 32 + quad * 8;
    unsigned short h[8], l[8];
#pragma unroll
    for (int j = 0; j < 8; ++j) {
        _Float16 hh, ll;
        f16split(src[j], hh, ll);
        union { _Float16 x; unsigned short u; } ch, cl;
        ch.x = hh; cl.x = ll;
        h[j] = ch.u; l[j] = cl.u;
    }
    *(uint4*)(wp1 + (size_t)p * 8) = *(const uint4*)h;
    *(uint4*)(wp2 + (size_t)p * 8) = *(const uint4*)l;
}

struct Aregs { f32x4 v[8]; };    // [m(2)][kk(2)][half(2)] — static indexing only
struct Bregs { f32x4 v[8]; };    // [plane(2)][i(4)]      — static indexing only

// ---- fused gate v3: raw-barrier pipeline, reg-staged B (T14), 2 blocks/CU ----
// Block = 256 thr = 4 waves; wave wv owns experts [wv*32, +32) (nt = wv*2+j),
// ALL 32 tokens (2 m-tiles). Grid 512 -> 2 blocks/CU (LDS 64 KB each).
// Pipeline: B global->reg issued 2 chunks ahead; ds_write publishes 1 chunk ahead;
// raw s_barrier (NO vmcnt drain — that drain was R0/R1's 5x serialization).
// Compiler inserts exact counted vmcnt waits for reg uses (all loads are visible).
__global__ __launch_bounds__(256, 2) void moe_gate(const float* __restrict__ x,
                                                   const unsigned short* __restrict__ wp1,
                                                   const unsigned short* __restrict__ wp2,
                                                   float* __restrict__ out_idx,
                                                   float* __restrict__ out_w) {
    // bsm[buf][plane][8192] u16: per buf, plane layout [2kk][8nt][64 lane][8 f16] = 16 KB
    __shared__ __align__(16) unsigned short bsm[2][2][8192];   // 64 KB
    float* epil = (float*)bsm;                                  // [32][132] f32 = 16.9 KB union

    const int tid  = threadIdx.x;
    const int lane = tid & 63;
    const int wv   = tid >> 6;        // expert group 0..3
    const int col  = lane & 15;       // A: token-in-tile, B: expert-in-tile, D: col
    const int quad = lane >> 4;       // A/B: k-seg, D: row group
    const long tok0 = (long)blockIdx.x * TM;

    // lane reads x[token = m*16+col][k = ch*64 + kk*32 + quad*8 .. +8]
    const float* xg = x + (tok0 + col) * (long)HDIM + quad * 8;

    f32x4 acc[2][2], accc[2][2];      // [m][j] main + cross (static-indexed)
#pragma unroll
    for (int m = 0; m < 2; ++m)
#pragma unroll
        for (int j = 0; j < 2; ++j) { acc[m][j] = (f32x4){0,0,0,0}; accc[m][j] = (f32x4){0,0,0,0}; }

    f16x8 af1[2][2], af2[2][2];       // [kk][m] hi/lo planes

    auto loadA = [&](int ch, Aregs& A) {
#pragma unroll
        for (int m = 0; m < 2; ++m) {
            const float* p = xg + (size_t)m * 16 * HDIM + ch * BK;
            A.v[m * 4 + 0] = *(const f32x4*)(p);
            A.v[m * 4 + 1] = *(const f32x4*)(p + 4);
            A.v[m * 4 + 2] = *(const f32x4*)(p + 32);
            A.v[m * 4 + 3] = *(const f32x4*)(p + 36);
        }
    };
    auto loadB = [&](int ch, Bregs& B) {
#pragma unroll
        for (int i = 0; i < 8; ++i) {
            const unsigned short* s = (i < 4 ? wp1 : wp2) + (size_t)ch * 8192
                                    + ((size_t)((i & 3) * 256 + tid)) * 8;
            B.v[i] = *(const f32x4*)s;            // coalesced: consecutive tid -> consecutive 16 B
        }
    };
    auto writeB = [&](Bregs& B, unsigned short* buf) {
#pragma unroll
        for (int i = 0; i < 8; ++i)                // lane-contiguous 16 B -> conflict-free
            *(f32x4*)(buf + (i >> 2) * 8192 + ((i & 3) * 256 + tid) * 8) = B.v[i];
    };
    auto splitA = [&](Aregs& A) {
#pragma unroll
        for (int m = 0; m < 2; ++m)
#pragma unroll
            for (int kk = 0; kk < 2; ++kk) {
                f32x4 v0 = A.v[m * 4 + kk * 2 + 0];
                f32x4 v1 = A.v[m * 4 + kk * 2 + 1];
#pragma unroll
                for (int j = 0; j < 8; ++j) {
                    float f = (j < 4) ? v0[j] : v1[j - 4];
                    _Float16 hh, ll;
                    f16split(f, hh, ll);
                    af1[kk][m][j] = hh;
                    af2[kk][m][j] = ll;
                }
            }
    };

    Aregs A;            // A: 1-deep prefetch (issue ch+1, use next iter)
    Bregs B0, B1;       // B: 2-deep prefetch, ping-pong sets

    // ---- prologue: A(0), B(0), B(1) in flight; publish B(0) ----
    loadA(0, A);
    loadB(0, B0);
    loadB(1, B1);
    writeB(B0, &bsm[0][0][0]);         // compiler vmcnt wait drains A(0),B(0); leaves B(1)
    asm volatile("s_waitcnt lgkmcnt(0)" ::: "memory");
    __builtin_amdgcn_s_barrier();      // bsm[0] ready; raw barrier: B(1) stays in flight

    // iter ch: read bsm[p]; issue A(ch+1), B(ch+2)->Bset; ds_write B(ch+1) (Bprev)->bsm[p^1]
    auto body = [&](int ch, Bregs& Bset, Bregs& Bprev,
                    const unsigned short* bufR, unsigned short* bufW) {
        splitA(A);                                  // waits only A(ch) (oldest); prefetches stay
        if (ch + 1 < NCH) loadA(ch + 1, A);
        if (ch + 2 < NCH) loadB(ch + 2, Bset);

        const unsigned short* b1 = bufR;
        const unsigned short* b2 = bufR + 8192;
#pragma unroll
        for (int kk = 0; kk < 2; ++kk)
#pragma unroll
            for (int j = 0; j < 2; ++j) {
                const int nt = wv * 2 + j;
                const int bo = ((kk * 8 + nt) * 64 + lane) * 8;   // lane-contiguous b128
                f16x8 bf1 = *(const f16x8*)(b1 + bo);
                f16x8 bf2 = *(const f16x8*)(b2 + bo);
#pragma unroll
                for (int m = 0; m < 2; ++m) {
                    acc[m][j]  = __builtin_amdgcn_mfma_f32_16x16x32_f16(af1[kk][m], bf1, acc[m][j],  0, 0, 0);
                    accc[m][j] = __builtin_amdgcn_mfma_f32_16x16x32_f16(af1[kk][m], bf2, accc[m][j], 0, 0, 0);
                    accc[m][j] = __builtin_amdgcn_mfma_f32_16x16x32_f16(af2[kk][m], bf1, accc[m][j], 0, 0, 0);
                }
            }

        if (ch + 1 < NCH) writeB(Bprev, bufW);      // waits B(ch+1) regs; leaves A(ch+1),B(ch+2)
        asm volatile("s_waitcnt lgkmcnt(0)" ::: "memory");
        __builtin_amdgcn_s_barrier();               // publish bufW; no vmcnt drain
    };

    for (int ch = 0; ch < NCH; ch += 2) {
        body(ch,     B0, B1, &bsm[0][0][0], &bsm[1][0][0]);   // p=0
        body(ch + 1, B1, B0, &bsm[1][0][0], &bsm[0][0][0]);   // p=1
    }
    __syncthreads();   // full drain before LDS reuse (nothing outstanding; safety)

    // ---- epilogue: logits -> LDS; D layout: token = m*16+quad*4+r, expert = (wv*2+j)*16+col
#pragma unroll
    for (int m = 0; m < 2; ++m)
#pragma unroll
        for (int j = 0; j < 2; ++j)
#pragma unroll
            for (int r = 0; r < 4; ++r)
                epil[(m * 16 + quad * 4 + r) * 132 + (wv * 2 + j) * 16 + col] =
                    acc[m][j][r] + accc[m][j][r] * INV_SPLIT_SCALE;
    __syncthreads();

    // ---- top-8 + renorm softmax: 8 tokens per wave (butterfly verified R1-R8) ----
    for (int i = 0; i < 8; ++i) {
        const int t = wv * 8 + i;
        float2 p = *(const float2*)(epil + t * 132 + 2 * lane);
        float v0 = p.x, v1 = p.y;
        const int i0 = 2 * lane, i1 = 2 * lane + 1;

        float topv[TOPK];
        int topi[TOPK];
#pragma unroll
        for (int s = 0; s < TOPK; ++s) {
            float mv = (v0 >= v1) ? v0 : v1;          // tie -> smaller index
            int   mi = (v0 >= v1) ? i0 : i1;
#pragma unroll
            for (int off = 32; off >= 1; off >>= 1) {
                float ov = __shfl_xor(mv, off);
                int   oi = __shfl_xor(mi, off);
                if (ov > mv || (ov == mv && oi < mi)) { mv = ov; mi = oi; }
            }
            topv[s] = mv; topi[s] = mi;
            if (i0 == mi) v0 = -INFINITY;
            if (i1 == mi) v1 = -INFINITY;
        }

        const float m = topv[0];
        float sum = 0.f;
#pragma unroll
        for (int s = 0; s < TOPK; ++s) sum += expf(topv[s] - m);
        const float inv = 1.f / sum;

        float myv = topv[0]; int myi = topi[0];
#pragma unroll
        for (int s = 1; s < TOPK; ++s)
            if (lane == s) { myv = topv[s]; myi = topi[s]; }

        if (lane < TOPK) {
            long tok = tok0 + t;
            out_idx[tok * TOPK + lane] = (float)myi;
            out_w[tok * TOPK + lane]   = expf(myv - m) * inv;
        }
    }
}

extern "C" void kernel_launch(void* const* d_in, const int* in_sizes, int n_in,
                              void* d_out, int out_size, void* d_ws, size_t ws_size,
                              hipStream_t stream) {
    const float* x = (const float*)d_in[0];   // [4,4096,2048] fp32
    const float* w = (const float*)d_in[1];   // [128,2048] fp32
    float* out = (float*)d_out;               // [T*8 idx][T*8 weights] flat fp32

    unsigned short* wp1 = (unsigned short*)d_ws;           // 512 KB packed hi
    unsigned short* wp2 = wp1 + (size_t)NEXP * HDIM;       // 512 KB packed lo

    pack_w<<<(64 * 8 * 64) / 256, 256, 0, stream>>>(w, wp1, wp2);
    moe_gate<<<T_TOKENS / TM, 256, 0, stream>>>(x, wp1, wp2, out, out + (size_t)T_TOKENS * TOPK);
}

// Round 3
// 283.117 us; speedup vs baseline: 1.0124x; 1.0124x over previous
//
#include <hip/hip_runtime.h>
#include <math.h>

#define T_TOKENS 16384
#define HDIM     2048
#define NEXP     128
#define TOPK     8

#define BK    64                 // k per chunk (2 MFMA k-steps)
#define NCH   (HDIM / BK)        // 32 chunks
#define TM    32                 // tokens per block

#define F16_MIN_NORM    6.1035156e-05f
#define SPLIT_SCALE     4096.0f
#define INV_SPLIT_SCALE 2.44140625e-04f   // 2^-12

typedef __attribute__((ext_vector_type(8))) _Float16 f16x8;  // A/B frag: 4 VGPR
typedef __attribute__((ext_vector_type(4))) float    f32x4;  // C/D frag + loads

// x = hi + lo*2^-12 (f16 RNE each); residual <= 2^-24|x|. Numerics verified R3-R8.
__device__ __forceinline__ void f16split(float f, _Float16& hi, _Float16& lo) {
    _Float16 h = (_Float16)f;
    float back = (float)h;
    if (fabsf(f) < F16_MIN_NORM) { h = (_Float16)0.f; back = 0.f; }
    lo = (_Float16)((f - back) * SPLIT_SCALE);
    hi = h;
}

// ---- prep: split w AND repack into MFMA B-frag order (verified R5-R8, unchanged) ----
// packed[s]: ((kk*8 + nt)*64 + lane) * 8 f16; kk = global 32-k step, nt = expert/16.
__global__ __launch_bounds__(256) void pack_w(const float* __restrict__ w,
                                              unsigned short* __restrict__ wp1,
                                              unsigned short* __restrict__ wp2) {
    int p = blockIdx.x * 256 + threadIdx.x;       // 0 .. 64*8*64-1
    int lane = p & 63, nt = (p >> 6) & 7, kk = p >> 9;
    int col = lane & 15, quad = lane >> 4;
    const float* src = w + (size_t)(nt * 16 + col) * HDIM + kk * 32 + quad * 8;
    unsigned short h[8], l[8];
#pragma unroll
    for (int j = 0; j < 8; ++j) {
        _Float16 hh, ll;
        f16split(src[j], hh, ll);
        union { _Float16 x; unsigned short u; } ch, cl;
        ch.x = hh; cl.x = ll;
        h[j] = ch.u; l[j] = cl.u;
    }
    *(uint4*)(wp1 + (size_t)p * 8) = *(const uint4*)h;
    *(uint4*)(wp2 + (size_t)p * 8) = *(const uint4*)l;
}

// ---- fused gate v4: T3/T4 — gload_lds double-buffer B, raw barriers, counted vmcnt ----
// Block = 256 thr = 4 waves; wave wv owns experts [wv*32, +32), all 32 tokens.
// Grid 512 -> 2 blocks/CU (2x 64 KB LDS = 128 <= 160). B staging uses global_load_lds:
// zero VGPR cost -> compiler CANNOT collapse the pipeline (R2's failure). In-flight
// state is tracked only by vmcnt; raw s_barrier never drains it; hand-counted
// s_waitcnt vmcnt(N) drains exactly one stage behind (never 0 in the loop).
// Issue ledger per chunk ch (my wave): [A(ch+1): 8 loads] ... barrier1 ...
// [stage(ch+2): 8 gload_lds] -> vmcnt(16) leaves A(ch+1)+stage(ch+2), drains stage(ch+1).
__global__ __launch_bounds__(256, 2) void moe_gate(const float* __restrict__ x,
                                                   const unsigned short* __restrict__ wp1,
                                                   const unsigned short* __restrict__ wp2,
                                                   float* __restrict__ out_idx,
                                                   float* __restrict__ out_w) {
    // bsm[buf][plane][8192] u16; plane layout [2kk][8nt][64 lane][8 f16] = 16 KB
    __shared__ __align__(16) unsigned short bsm[2][2][8192];   // 64 KB
    float* epil = (float*)bsm;                                  // [32][132] f32 union

    const int tid  = threadIdx.x;
    const int lane = tid & 63;
    const int wv   = tid >> 6;        // expert group 0..3
    const int col  = lane & 15;       // A: token-in-tile, B: expert-in-tile, D: col
    const int quad = lane >> 4;       // A/B: k-seg, D: row group
    const long tok0 = (long)blockIdx.x * TM;

    // lane reads x[token = m*16+col][k = ch*64 + kk*32 + quad*8 .. +8]
    const float* xg = x + (tok0 + col) * (long)HDIM + quad * 8;

    f32x4 acc[2][2], accc[2][2];      // [m][j] main + cross (static-indexed)
#pragma unroll
    for (int m = 0; m < 2; ++m)
#pragma unroll
        for (int j = 0; j < 2; ++j) { acc[m][j] = (f32x4){0,0,0,0}; accc[m][j] = (f32x4){0,0,0,0}; }

    f32x4 Av[8];                      // A staging regs [m(2)][kk(2)][half(2)] — static idx
    f16x8 af1[2][2], af2[2][2];       // [kk][m] hi/lo planes

    auto loadA = [&](int ch) {        // 8 vmem loads
#pragma unroll
        for (int m = 0; m < 2; ++m) {
            const float* p = xg + (size_t)m * 16 * HDIM + ch * BK;
            Av[m * 4 + 0] = *(const f32x4*)(p);
            Av[m * 4 + 1] = *(const f32x4*)(p + 4);
            Av[m * 4 + 2] = *(const f32x4*)(p + 32);
            Av[m * 4 + 3] = *(const f32x4*)(p + 36);
        }
    };
    auto splitA = [&]() {             // consume Av -> af planes (32 f16splits)
#pragma unroll
        for (int m = 0; m < 2; ++m)
#pragma unroll
            for (int kk = 0; kk < 2; ++kk) {
                f32x4 v0 = Av[m * 4 + kk * 2 + 0];
                f32x4 v1 = Av[m * 4 + kk * 2 + 1];
#pragma unroll
                for (int j = 0; j < 8; ++j) {
                    float f = (j < 4) ? v0[j] : v1[j - 4];
                    _Float16 hh, ll;
                    f16split(f, hh, ll);
                    af1[kk][m][j] = hh;
                    af2[kk][m][j] = ll;
                }
            }
    };
    auto stageB = [&](int ch, int buf) {   // 8 gload_lds, 16 B each; zero VGPR
        const unsigned short* s1 = wp1 + (size_t)ch * 8192;
        const unsigned short* s2 = wp2 + (size_t)ch * 8192;
        unsigned short* d1 = &bsm[buf][0][0];
        unsigned short* d2 = &bsm[buf][1][0];
#pragma unroll
        for (int i = 0; i < 4; ++i) {
            const int off = (i * 256 + tid) * 8;   // f16 units, 16 B per thread
            __builtin_amdgcn_global_load_lds((const __attribute__((address_space(1))) void*)(s1 + off),
                                             (__attribute__((address_space(3))) void*)(d1 + off), 16, 0, 0);
            __builtin_amdgcn_global_load_lds((const __attribute__((address_space(1))) void*)(s2 + off),
                                             (__attribute__((address_space(3))) void*)(d2 + off), 16, 0, 0);
        }
    };
    // compute(ch, p): split A(ch), prefetch A(ch+1), MFMA from bsm[p], barrier1.
    // All ds_read results feed MFMAs before barrier1 => reads complete before any
    // wave passes it => safe to DMA-overwrite bsm[p] after.
    auto compute = [&](int ch, int p) {
        splitA();                                  // compiler-counted wait: drains A(ch) only
        if (ch + 1 < NCH) loadA(ch + 1);
        const unsigned short* b1 = &bsm[p][0][0];
        const unsigned short* b2 = &bsm[p][1][0];
#pragma unroll
        for (int kk = 0; kk < 2; ++kk)
#pragma unroll
            for (int j = 0; j < 2; ++j) {
                const int nt = wv * 2 + j;
                const int bo = ((kk * 8 + nt) * 64 + lane) * 8;   // lane-contig b128
                f16x8 bf1 = *(const f16x8*)(b1 + bo);
                f16x8 bf2 = *(const f16x8*)(b2 + bo);
#pragma unroll
                for (int m = 0; m < 2; ++m) {
                    acc[m][j]  = __builtin_amdgcn_mfma_f32_16x16x32_f16(af1[kk][m], bf1, acc[m][j],  0, 0, 0);
                    accc[m][j] = __builtin_amdgcn_mfma_f32_16x16x32_f16(af1[kk][m], bf2, accc[m][j], 0, 0, 0);
                    accc[m][j] = __builtin_amdgcn_mfma_f32_16x16x32_f16(af2[kk][m], bf1, accc[m][j], 0, 0, 0);
                }
            }
        asm volatile("" ::: "memory");             // pin load/ds ops this side
        __builtin_amdgcn_s_barrier();              // barrier1: bsm[p] reads done (raw)
    };

    // ---- prologue: A(0) + stage(0)+stage(1) in flight ----
    loadA(0);                          // 8 vmem (oldest)
    stageB(0, 0);                      // 8
    stageB(1, 1);                      // 8
    asm volatile("s_waitcnt vmcnt(8)" ::: "memory");   // drain A(0)+stage(0); leave stage(1)
    __builtin_amdgcn_s_barrier();      // bsm[0] published

    // ---- main loop: ch = 0..29, unrolled x2 so buffer index is static ----
    for (int ch = 0; ch < NCH - 2; ch += 2) {
        compute(ch, 0);
        stageB(ch + 2, 0);                                     // 8 gload_lds into just-freed buf
        asm volatile("s_waitcnt vmcnt(16)" ::: "memory");      // drain stage(ch+1); leave A+stage
        __builtin_amdgcn_s_barrier();                          // publish bsm[1]
        compute(ch + 1, 1);
        if (ch + 3 < NCH) stageB(ch + 3, 1);
        asm volatile("s_waitcnt vmcnt(16)" ::: "memory");      // drain stage(ch+2)
        __builtin_amdgcn_s_barrier();                          // publish bsm[0]
    }
    // ---- tail: ch = 30 (reads bsm[0]; stage(31) still in flight at entry? no: drained) ----
    compute(NCH - 2, 0);                                       // ch=30
    asm volatile("s_waitcnt vmcnt(8)" ::: "memory");           // drain stage(31); leave A(31)
    __builtin_amdgcn_s_barrier();                              // publish bsm[1]
    compute(NCH - 1, 1);                                       // ch=31 (no loadA, no stage)
    __syncthreads();                                           // full drain before LDS reuse

    // ---- epilogue: logits -> LDS; D layout: token = m*16+quad*4+r, expert = (wv*2+j)*16+col
#pragma unroll
    for (int m = 0; m < 2; ++m)
#pragma unroll
        for (int j = 0; j < 2; ++j)
#pragma unroll
            for (int r = 0; r < 4; ++r)
                epil[(m * 16 + quad * 4 + r) * 132 + (wv * 2 + j) * 16 + col] =
                    acc[m][j][r] + accc[m][j][r] * INV_SPLIT_SCALE;
    __syncthreads();

    // ---- top-8 + renorm softmax: 8 tokens per wave (butterfly verified R1-R8) ----
    for (int i = 0; i < 8; ++i) {
        const int t = wv * 8 + i;
        float2 p = *(const float2*)(epil + t * 132 + 2 * lane);
        float v0 = p.x, v1 = p.y;
        const int i0 = 2 * lane, i1 = 2 * lane + 1;

        float topv[TOPK];
        int topi[TOPK];
#pragma unroll
        for (int s = 0; s < TOPK; ++s) {
            float mv = (v0 >= v1) ? v0 : v1;          // tie -> smaller index
            int   mi = (v0 >= v1) ? i0 : i1;
#pragma unroll
            for (int off = 32; off >= 1; off >>= 1) {
                float ov = __shfl_xor(mv, off);
                int   oi = __shfl_xor(mi, off);
                if (ov > mv || (ov == mv && oi < mi)) { mv = ov; mi = oi; }
            }
            topv[s] = mv; topi[s] = mi;
            if (i0 == mi) v0 = -INFINITY;
            if (i1 == mi) v1 = -INFINITY;
        }

        const float m = topv[0];
        float sum = 0.f;
#pragma unroll
        for (int s = 0; s < TOPK; ++s) sum += expf(topv[s] - m);
        const float inv = 1.f / sum;

        float myv = topv[0]; int myi = topi[0];
#pragma unroll
        for (int s = 1; s < TOPK; ++s)
            if (lane == s) { myv = topv[s]; myi = topi[s]; }

        if (lane < TOPK) {
            long tok = tok0 + t;
            out_idx[tok * TOPK + lane] = (float)myi;
            out_w[tok * TOPK + lane]   = expf(myv - m) * inv;
        }
    }
}

extern "C" void kernel_launch(void* const* d_in, const int* in_sizes, int n_in,
                              void* d_out, int out_size, void* d_ws, size_t ws_size,
                              hipStream_t stream) {
    const float* x = (const float*)d_in[0];   // [4,4096,2048] fp32
    const float* w = (const float*)d_in[1];   // [128,2048] fp32
    float* out = (float*)d_out;               // [T*8 idx][T*8 weights] flat fp32

    unsigned short* wp1 = (unsigned short*)d_ws;           // 512 KB packed hi
    unsigned short* wp2 = wp1 + (size_t)NEXP * HDIM;       // 512 KB packed lo

    pack_w<<<(64 * 8 * 64) / 256, 256, 0, stream>>>(w, wp1, wp2);
    moe_gate<<<T_TOKENS / TM, 256, 0, stream>>>(x, wp1, wp2, out, out + (size_t)T_TOKENS * TOPK);
}

// Round 4
// 274.818 us; speedup vs baseline: 1.0430x; 1.0302x over previous
//
#include <hip/hip_runtime.h>
#include <math.h>

#define T_TOKENS 16384
#define HDIM     2048
#define NEXP     128
#define TOPK     8

#define BK    64                 // k per chunk (2 MFMA k-steps)
#define NCH   (HDIM / BK)        // 32 chunks
#define TM    32                 // tokens per block

#define F16_MIN_NORM    6.1035156e-05f
#define SPLIT_SCALE     4096.0f
#define INV_SPLIT_SCALE 2.44140625e-04f   // 2^-12

typedef __attribute__((ext_vector_type(8))) _Float16 f16x8;  // A/B frag: 4 VGPR
typedef __attribute__((ext_vector_type(4))) float    f32x4;  // C/D frag + loads

// x = hi + lo*2^-12 (f16 RNE each); residual <= 2^-24|x|. Numerics verified R3-R8.
__device__ __forceinline__ void f16split(float f, _Float16& hi, _Float16& lo) {
    _Float16 h = (_Float16)f;
    float back = (float)h;
    if (fabsf(f) < F16_MIN_NORM) { h = (_Float16)0.f; back = 0.f; }
    lo = (_Float16)((f - back) * SPLIT_SCALE);
    hi = h;
}

// ---- prep: split w AND repack into MFMA B-frag order (verified R5-R8, unchanged) ----
// packed[s]: ((kk*8 + nt)*64 + lane) * 8 f16; kk = global 32-k step, nt = expert/16.
__global__ __launch_bounds__(256) void pack_w(const float* __restrict__ w,
                                              unsigned short* __restrict__ wp1,
                                              unsigned short* __restrict__ wp2) {
    int p = blockIdx.x * 256 + threadIdx.x;       // 0 .. 64*8*64-1
    int lane = p & 63, nt = (p >> 6) & 7, kk = p >> 9;
    int col = lane & 15, quad = lane >> 4;
    const float* src = w + (size_t)(nt * 16 + col) * HDIM + kk * 32 + quad * 8;
    unsigned short h[8], l[8];
#pragma unroll
    for (int j = 0; j < 8; ++j) {
        _Float16 hh, ll;
        f16split(src[j], hh, ll);
        union { _Float16 x; unsigned short u; } ch, cl;
        ch.x = hh; cl.x = ll;
        h[j] = ch.u; l[j] = cl.u;
    }
    *(uint4*)(wp1 + (size_t)p * 8) = *(const uint4*)h;
    *(uint4*)(wp2 + (size_t)p * 8) = *(const uint4*)l;
}

struct ARegs { f32x4 v[8]; };    // [m(2)][kk(2)][half(2)] — static indexing only
struct BRegs { f16x8 v[8]; };    // [(kk*2+j)*2+plane]     — static indexing only

// ---- fused gate v5: barrier-free main loop, B direct global->reg (L2-hot) ----
// Key insight (R3 post-mortem): B fragments are per-wave DISJOINT (nt = wv*2+j) —
// LDS staging shared nothing, so all staging/barrier machinery was pure serialization.
// Now: each wave streams its own B-frags from L2 (wp = 1 MB, L2-resident; packed
// layout IS the fragment layout -> lane-contiguous 16 B/lane coalesced loads) and
// A from global, both ping-pong double-buffered 2 chunks deep in registers with
// compiler-counted waits. Zero main-loop barriers: 8 waves/CU free-run. LDS only
// for the epilogue exchange (17 KB). Grid 512 -> 2 blocks/CU (grid-capped), so
// VGPR up to 256 is free — spent on the double buffers.
__global__ __launch_bounds__(256, 2) void moe_gate(const float* __restrict__ x,
                                                   const unsigned short* __restrict__ wp1,
                                                   const unsigned short* __restrict__ wp2,
                                                   float* __restrict__ out_idx,
                                                   float* __restrict__ out_w) {
    __shared__ __align__(16) float epil[TM * 132];   // [32][132] f32 = 16.9 KB

    const int tid  = threadIdx.x;
    const int lane = tid & 63;
    const int wv   = tid >> 6;        // expert group 0..3
    const int col  = lane & 15;       // A: token-in-tile, B: expert-in-tile, D: col
    const int quad = lane >> 4;       // A/B: k-seg, D: row group
    const long tok0 = (long)blockIdx.x * TM;

    // lane reads x[token = m*16+col][k = ch*64 + kk*32 + quad*8 .. +8]
    const float* xg = x + (tok0 + col) * (long)HDIM + quad * 8;

    f32x4 acc[2][2], accc[2][2];      // [m][j] main + cross (static-indexed)
#pragma unroll
    for (int m = 0; m < 2; ++m)
#pragma unroll
        for (int j = 0; j < 2; ++j) { acc[m][j] = (f32x4){0,0,0,0}; accc[m][j] = (f32x4){0,0,0,0}; }

    f16x8 af1[2][2], af2[2][2];       // [kk][m] hi/lo planes (shared by both halves)

    auto loadA = [&](int ch, ARegs& A) {    // 8 coalesced 16 B loads (16 rows x 128 B)
#pragma unroll
        for (int m = 0; m < 2; ++m) {
            const float* p = xg + (size_t)m * 16 * HDIM + ch * BK;
            A.v[m * 4 + 0] = *(const f32x4*)(p);
            A.v[m * 4 + 1] = *(const f32x4*)(p + 4);
            A.v[m * 4 + 2] = *(const f32x4*)(p + 32);
            A.v[m * 4 + 3] = *(const f32x4*)(p + 36);
        }
    };
    auto loadB = [&](int ch, BRegs& B) {    // 8 lane-contiguous 16 B loads (1 KB/instr, L2)
        const size_t cho = (size_t)ch * 8192;
#pragma unroll
        for (int kk = 0; kk < 2; ++kk)
#pragma unroll
            for (int j = 0; j < 2; ++j) {
                const size_t o = cho + (size_t)(((kk * 8) + (wv * 2 + j)) * 64 + lane) * 8;
                B.v[(kk * 2 + j) * 2 + 0] = *(const f16x8*)(wp1 + o);
                B.v[(kk * 2 + j) * 2 + 1] = *(const f16x8*)(wp2 + o);
            }
    };
    auto splitA = [&](ARegs& A) {           // Av -> af planes (32 f16splits)
#pragma unroll
        for (int m = 0; m < 2; ++m)
#pragma unroll
            for (int kk = 0; kk < 2; ++kk) {
                f32x4 v0 = A.v[m * 4 + kk * 2 + 0];
                f32x4 v1 = A.v[m * 4 + kk * 2 + 1];
#pragma unroll
                for (int j = 0; j < 8; ++j) {
                    float f = (j < 4) ? v0[j] : v1[j - 4];
                    _Float16 hh, ll;
                    f16split(f, hh, ll);
                    af1[kk][m][j] = hh;
                    af2[kk][m][j] = ll;
                }
            }
    };
    auto mfmaStep = [&](BRegs& B) {
#pragma unroll
        for (int kk = 0; kk < 2; ++kk)
#pragma unroll
            for (int j = 0; j < 2; ++j) {
                f16x8 bf1 = B.v[(kk * 2 + j) * 2 + 0];
                f16x8 bf2 = B.v[(kk * 2 + j) * 2 + 1];
#pragma unroll
                for (int m = 0; m < 2; ++m) {
                    acc[m][j]  = __builtin_amdgcn_mfma_f32_16x16x32_f16(af1[kk][m], bf1, acc[m][j],  0, 0, 0);
                    accc[m][j] = __builtin_amdgcn_mfma_f32_16x16x32_f16(af1[kk][m], bf2, accc[m][j], 0, 0, 0);
                    accc[m][j] = __builtin_amdgcn_mfma_f32_16x16x32_f16(af2[kk][m], bf1, accc[m][j], 0, 0, 0);
                }
            }
    };

    ARegs A0, A1;                     // ping-pong sets: prefetch distance = 2 chunks
    BRegs B0, B1;

    loadA(0, A0); loadB(0, B0);
    loadA(1, A1); loadB(1, B1);

    for (int ch = 0; ch < NCH; ch += 2) {
        // even half: consume set0 (loaded 2 chunks ago), refill for ch+2
        splitA(A0);                               // compiler waits A(ch) only
        if (ch + 2 < NCH) loadA(ch + 2, A0);      // WAR: issues after split consumed regs
        mfmaStep(B0);                             // compiler waits B(ch) only
        if (ch + 2 < NCH) loadB(ch + 2, B0);
        // odd half
        splitA(A1);
        if (ch + 3 < NCH) loadA(ch + 3, A1);
        mfmaStep(B1);
        if (ch + 3 < NCH) loadB(ch + 3, B1);
    }

    // ---- epilogue: logits -> LDS; D layout: token = m*16+quad*4+r, expert = (wv*2+j)*16+col
    // Waves write disjoint expert columns; one barrier; then read full rows.
#pragma unroll
    for (int m = 0; m < 2; ++m)
#pragma unroll
        for (int j = 0; j < 2; ++j)
#pragma unroll
            for (int r = 0; r < 4; ++r)
                epil[(m * 16 + quad * 4 + r) * 132 + (wv * 2 + j) * 16 + col] =
                    acc[m][j][r] + accc[m][j][r] * INV_SPLIT_SCALE;
    __syncthreads();

    // ---- top-8 + renorm softmax: 8 tokens per wave (butterfly verified R1-R8) ----
    for (int i = 0; i < 8; ++i) {
        const int t = wv * 8 + i;
        float2 p = *(const float2*)(epil + t * 132 + 2 * lane);
        float v0 = p.x, v1 = p.y;
        const int i0 = 2 * lane, i1 = 2 * lane + 1;

        float topv[TOPK];
        int topi[TOPK];
#pragma unroll
        for (int s = 0; s < TOPK; ++s) {
            float mv = (v0 >= v1) ? v0 : v1;          // tie -> smaller index
            int   mi = (v0 >= v1) ? i0 : i1;
#pragma unroll
            for (int off = 32; off >= 1; off >>= 1) {
                float ov = __shfl_xor(mv, off);
                int   oi = __shfl_xor(mi, off);
                if (ov > mv || (ov == mv && oi < mi)) { mv = ov; mi = oi; }
            }
            topv[s] = mv; topi[s] = mi;
            if (i0 == mi) v0 = -INFINITY;
            if (i1 == mi) v1 = -INFINITY;
        }

        const float m = topv[0];
        float sum = 0.f;
#pragma unroll
        for (int s = 0; s < TOPK; ++s) sum += expf(topv[s] - m);
        const float inv = 1.f / sum;

        float myv = topv[0]; int myi = topi[0];
#pragma unroll
        for (int s = 1; s < TOPK; ++s)
            if (lane == s) { myv = topv[s]; myi = topi[s]; }

        if (lane < TOPK) {
            long tok = tok0 + t;
            out_idx[tok * TOPK + lane] = (float)myi;
            out_w[tok * TOPK + lane]   = expf(myv - m) * inv;
        }
    }
}

extern "C" void kernel_launch(void* const* d_in, const int* in_sizes, int n_in,
                              void* d_out, int out_size, void* d_ws, size_t ws_size,
                              hipStream_t stream) {
    const float* x = (const float*)d_in[0];   // [4,4096,2048] fp32
    const float* w = (const float*)d_in[1];   // [128,2048] fp32
    float* out = (float*)d_out;               // [T*8 idx][T*8 weights] flat fp32

    unsigned short* wp1 = (unsigned short*)d_ws;           // 512 KB packed hi
    unsigned short* wp2 = wp1 + (size_t)NEXP * HDIM;       // 512 KB packed lo

    pack_w<<<(64 * 8 * 64) / 256, 256, 0, stream>>>(w, wp1, wp2);
    moe_gate<<<T_TOKENS / TM, 256, 0, stream>>>(x, wp1, wp2, out, out + (size_t)T_TOKENS * TOPK);
}